// Round 9
// baseline (1420.626 us; speedup 1.0000x reference)
//
#include <hip/hip_runtime.h>
#include <hip/hip_bf16.h>
#include <math.h>

// Problem dims
#define BB 8
#define TT 16
#define HH 112
#define WW 112
#define CC 3
#define FF 16
#define HP 56
#define WP 56
#define HO 54
#define WO 54
#define NC 6

#define NPIX (BB*HO*WO)               // 23328
#define SPIX (HO*WO)                  // 2916
#define NPT  (BB*TT*SPIX)             // 373248  (b,t,pixel)
#define NBLK 384                      // persistent grid: 12 tiles x 8 b x 4 cg

// ws layout (float offsets)
#define POOLED_ELEMS (128*56*56*16)   // 6,422,528
#define HSTATE_ELEMS (BB*SPIX*16)     // 373,248
#define WPACK_ELEMS  18432            // wkpack 9216 + wrpack 9216, [cg][tap][ci][g][c4]

__device__ __forceinline__ float hsig(float x) {
    return fminf(fmaxf(0.2f*x + 0.5f, 0.0f), 1.0f);
}

// Device-scope grid barrier, one-shot counter per use (no generation race).
// Release: __threadfence() before arrive publishes this block's h writes
// (agent fence -> L2 writeback on gfx950). Acquire: fence after spin
// invalidates stale lines before reading neighbors' h.
__device__ __forceinline__ void grid_barrier(unsigned* cnt) {
    __syncthreads();
    if (threadIdx.x == 0) {
        __threadfence();
        __hip_atomic_fetch_add(cnt, 1u, __ATOMIC_ACQ_REL, __HIP_MEMORY_SCOPE_AGENT);
        while (__hip_atomic_load(cnt, __ATOMIC_RELAXED, __HIP_MEMORY_SCOPE_AGENT) < NBLK)
            __builtin_amdgcn_s_sleep(2);
        __threadfence();
    }
    __syncthreads();
}

// Kernel 0: repack both LSTM weight tensors into [cg][tap][ci][g][c4].
__global__ __launch_bounds__(256) void repack_kernel(
    const float* __restrict__ wk, const float* __restrict__ wr,
    float* __restrict__ wpack)
{
    int i = blockIdx.x * 256 + threadIdx.x;        // 72*256 = 18432 exact
    int idx = (i < 9216) ? i : i - 9216;
    int c4  = idx & 3;
    int g   = (idx >> 2) & 3;
    int ci  = (idx >> 4) & 15;
    int tap = (idx >> 8) % 9;
    int cg  = (idx >> 8) / 9;
    const float* src = (i < 9216) ? wk : wr;
    wpack[i] = src[tap*1024 + ci*64 + g*16 + (cg*4 + c4)];
}

// Kernel 1: fused 7x7 SAME conv (3->16) + bias + relu + 2x2 maxpool. (unchanged)
__global__ __launch_bounds__(256) void conv_pool_kernel(
    const float* __restrict__ x,      // [128,112,112,3]
    const float* __restrict__ cw,     // [7,7,3,16]
    const float* __restrict__ cb,     // [16]
    float* __restrict__ pooled)       // [128,56,56,16]
{
    int idx = blockIdx.x * 256 + threadIdx.x;   // 401408 exact
    int fr = idx / (HP*WP);
    int r  = idx % (HP*WP);
    int ph = r / WP, pw = r % WP;

    const float* xf = x + (size_t)fr * HH * WW * CC;

    float best[16];
    #pragma unroll
    for (int i = 0; i < 16; ++i) best[i] = -1e30f;

    for (int py = 0; py < 2; ++py) {
        for (int px = 0; px < 2; ++px) {
            int oh = 2*ph + py, ow = 2*pw + px;
            float acc[16];
            #pragma unroll
            for (int i = 0; i < 16; ++i) acc[i] = cb[i];
            for (int ky = 0; ky < 7; ++ky) {
                int ih = oh - 3 + ky;
                if (ih < 0 || ih >= HH) continue;
                for (int kx = 0; kx < 7; ++kx) {
                    int iw = ow - 3 + kx;
                    if (iw < 0 || iw >= WW) continue;
                    const float* xp = xf + ((size_t)ih * WW + iw) * CC;
                    const float* wp = cw + ((ky*7 + kx) * CC) * 16;
                    #pragma unroll
                    for (int ci = 0; ci < 3; ++ci) {
                        float a = xp[ci];
                        #pragma unroll
                        for (int fo = 0; fo < 16; ++fo)
                            acc[fo] += a * wp[ci*16 + fo];
                    }
                }
            }
            #pragma unroll
            for (int i = 0; i < 16; ++i) best[i] = fmaxf(best[i], acc[i]);
        }
    }

    float4* op = (float4*)(pooled + (size_t)idx * 16);
    #pragma unroll
    for (int v = 0; v < 4; ++v) {
        float4 o;
        o.x = fmaxf(best[v*4+0], 0.0f);
        o.y = fmaxf(best[v*4+1], 0.0f);
        o.z = fmaxf(best[v*4+2], 0.0f);
        o.w = fmaxf(best[v*4+3], 0.0f);
        op[v] = o;
    }
}

// Kernel 2a: precompute zx = conv3x3 VALID (pooled -> 64 gates) for ALL t. (unchanged)
__global__ __launch_bounds__(256, 4) void zx_all_kernel(
    const float* __restrict__ pooled,   // [128,56,56,16]
    const float* __restrict__ wkpack,   // [cg][tap][ci][g][c4]
    __hip_bfloat16* __restrict__ zx)    // [64][373248]
{
    int cg = blockIdx.y;                // 0..3 (channels cg*4 .. cg*4+3)
    const float* wcg = wkpack + cg * 2304;

    int pt = blockIdx.x * 256 + threadIdx.x;   // 1458*256 = 373248 exact
    int b  = pt / (TT*SPIX);
    int rt = pt % (TT*SPIX);
    int tt = rt / SPIX;
    int r  = rt % SPIX;
    int oh = r / WO, ow = r % WO;

    const float* pf = pooled + (size_t)(b*TT + tt) * HP * WP * 16;

    float acc[16];                      // [c4][g]
    #pragma unroll
    for (int i = 0; i < 16; ++i) acc[i] = 0.0f;

    #pragma unroll 1
    for (int tap = 0; tap < 9; ++tap) {
        int ky = tap / 3;
        int kx = tap - ky * 3;
        const float4* pp = (const float4*)(pf + ((size_t)(oh+ky) * WP + (ow+kx)) * 16);
        float a[16];
        #pragma unroll
        for (int v = 0; v < 4; ++v) {
            float4 x4 = pp[v];
            a[v*4+0] = x4.x; a[v*4+1] = x4.y; a[v*4+2] = x4.z; a[v*4+3] = x4.w;
        }
        const float* wt = wcg + tap * 256;
        #pragma unroll 1
        for (int q = 0; q < 4; ++q) {       // ci quarters: 64 scalar floats live
            const float* wc = wt + q * 64;
            #pragma unroll
            for (int u = 0; u < 4; ++u) {
                float av = a[q*4 + u];
                #pragma unroll
                for (int g = 0; g < 4; ++g) {
                    #pragma unroll
                    for (int c4 = 0; c4 < 4; ++c4)
                        acc[c4*4 + g] += av * wc[u*16 + g*4 + c4];
                }
            }
        }
    }

    #pragma unroll
    for (int g = 0; g < 4; ++g) {
        #pragma unroll
        for (int c4 = 0; c4 < 4; ++c4) {
            size_t o = (size_t)(g*16 + cg*4 + c4) * NPT + pt;
            zx[o] = __float2bfloat16(acc[c4*4 + g]);
        }
    }
}

// Kernel 2b: ALL 16 ConvLSTM steps in one persistent kernel.
// Block = 18x14 pixel tile x 4-ch group; grid 384 blocks (co-residency:
// launch_bounds(256,4) caps VGPR at 128 -> 4 blocks/CU capacity = 1024 >= 384;
// LDS 20.5 KB x 4 = 82 KB < 160 KB). Grid barrier between steps via one-shot
// device-scope counters. c-state lives in REGISTERS across all steps (no cst
// buffer). Kills 15 kernel-launch overheads (~10 us each) that dominated R7.
__global__ __launch_bounds__(256, 4) void lstm_scan_kernel(
    const __hip_bfloat16* __restrict__ zx,  // [64][373248]
    float* __restrict__ hA,                 // [8,54,54,16] (zeroed: h0)
    float* __restrict__ hB,
    const float* __restrict__ wrpack,       // [cg][tap][ci][g][c4]
    const float* __restrict__ bias,         // [64]
    unsigned* __restrict__ barriers)        // [TT] zeroed counters
{
    int bid = blockIdx.x;
    int tileid = bid % 12;        // 0..11
    int tx = tileid % 3;          // 3 tiles x 18 cols = 54 exact
    int ty = tileid / 3;          // 4 tiles x 14 rows (covers 56, top 2 idle)
    int b  = (bid / 12) % 8;
    int cg = bid / 96;            // block-uniform -> scalar weights
    const float* wcg = wrpack + cg * 2304;

    int tid = threadIdx.x;
    int lx = tid % 18, ly = tid / 18;   // ly 0..14 (tid<252)
    int gx = tx*18 + lx;                // 0..53 always
    int gy = ty*14 + ly;
    bool active = (tid < 252) && (gy < HO);

    int r = gy * WO + gx;
    size_t ptbase = (size_t)b * (TT*SPIX) + r;
    size_t obase  = ((size_t)(b * SPIX + r)) * 16 + cg*4;

    float b_i[4], b_f[4], b_g[4], b_o[4];
    #pragma unroll
    for (int c4 = 0; c4 < 4; ++c4) {
        int ch = cg*4 + c4;
        b_i[c4] = bias[ 0 + ch]; b_f[c4] = bias[16 + ch];
        b_g[c4] = bias[32 + ch]; b_o[c4] = bias[48 + ch];
    }

    float4 creg = make_float4(0.f, 0.f, 0.f, 0.f);   // c0 = 0, in registers
    __shared__ float htile[320*16];                  // 20.5 KB

    #pragma unroll 1
    for (int t = 0; t < TT; ++t) {
        const float* hin = (t & 1) ? hB : hA;
        float*      hout = (t & 1) ? hA : hB;
        const float* hb  = hin + (size_t)b * SPIX * 16;

        // Stage h halo tile: rows gy0-1..gy0+14 (16), cols gx0-1..gx0+18 (20).
        {
            int gy0 = ty*14 - 1, gx0 = tx*18 - 1;
            for (int i = tid; i < 320; i += 256) {
                int iy = i / 20, ix = i % 20;
                int hy = gy0 + iy, hx = gx0 + ix;
                bool ok = (hy >= 0) & (hy < HO) & (hx >= 0) & (hx < WO);
                float4* dst = (float4*)&htile[i*16];
                const float4* src = (const float4*)(hb + ((size_t)hy * WO + hx) * 16);
                #pragma unroll
                for (int v = 0; v < 4; ++v)
                    dst[v] = ok ? src[v] : make_float4(0.f, 0.f, 0.f, 0.f);
            }
        }
        __syncthreads();

        if (active) {
            size_t pt = ptbase + (size_t)t * SPIX;
            float z[16];                        // [g][c4]
            #pragma unroll
            for (int g = 0; g < 4; ++g)
                #pragma unroll
                for (int c4 = 0; c4 < 4; ++c4)
                    z[g*4 + c4] = __bfloat162float(zx[(size_t)(g*16 + cg*4 + c4) * NPT + pt]);

            float acc[16];                      // [c4][g]
            #pragma unroll
            for (int i = 0; i < 16; ++i) acc[i] = 0.0f;

            #pragma unroll 1
            for (int tap = 0; tap < 9; ++tap) {
                int ky = tap / 3;
                int kx = tap - ky * 3;
                const float4* hp4 = (const float4*)&htile[((ly + ky)*20 + (lx + kx))*16];
                float h[16];
                #pragma unroll
                for (int v = 0; v < 4; ++v) {
                    float4 t4 = hp4[v];
                    h[v*4+0] = t4.x; h[v*4+1] = t4.y; h[v*4+2] = t4.z; h[v*4+3] = t4.w;
                }
                const float* wt = wcg + tap * 256;
                #pragma unroll 1
                for (int q = 0; q < 4; ++q) {   // ci quarters: 64 scalar floats live
                    const float* wc = wt + q * 64;
                    #pragma unroll
                    for (int u = 0; u < 4; ++u) {
                        float hv = h[q*4 + u];
                        #pragma unroll
                        for (int g = 0; g < 4; ++g) {
                            #pragma unroll
                            for (int c4 = 0; c4 < 4; ++c4)
                                acc[c4*4 + g] += hv * wc[u*16 + g*4 + c4];
                        }
                    }
                }
            }

            float* cold = &creg.x;
            float4 hnew4; float* hn4 = &hnew4.x;
            #pragma unroll
            for (int c4 = 0; c4 < 4; ++c4) {
                float iv = hsig(z[0*4+c4] + acc[c4*4+0] + b_i[c4]);
                float fv = hsig(z[1*4+c4] + acc[c4*4+1] + b_f[c4]);
                float gv = tanhf(z[2*4+c4] + acc[c4*4+2] + b_g[c4]);
                float ov = hsig(z[3*4+c4] + acc[c4*4+3] + b_o[c4]);
                float cn = fv * cold[c4] + iv * gv;
                cold[c4] = cn;
                hn4[c4] = ov * tanhf(cn);
            }
            *(float4*)&hout[obase] = hnew4;
        }

        grid_barrier(&barriers[t]);
    }
}

// Kernel 3: spatial mean over 54x54 -> dense(16->6) -> softmax. One block per b.
__global__ __launch_bounds__(256) void head_kernel(
    const float* __restrict__ h,    // [8,54,54,16]
    const float* __restrict__ dw,   // [16,6]
    const float* __restrict__ db,   // [6]
    float* __restrict__ out)        // [8,6]
{
    int b = blockIdx.x;
    int tid = threadIdx.x;
    const float* hb = h + (size_t)b * SPIX * 16;
    float s = 0.0f;
    for (int i = tid; i < SPIX*16; i += 256) s += hb[i];
    __shared__ float red[256];
    red[tid] = s;
    __syncthreads();
    for (int st = 128; st >= 16; st >>= 1) {
        if (tid < st) red[tid] += red[tid + st];
        __syncthreads();
    }
    __shared__ float logits[8];
    if (tid < NC) {
        float l = db[tid];
        #pragma unroll
        for (int ch = 0; ch < 16; ++ch)
            l += (red[ch] * (1.0f/2916.0f)) * dw[ch*NC + tid];
        logits[tid] = l;
    }
    __syncthreads();
    if (tid < NC) {
        float m = -1e30f;
        for (int k = 0; k < NC; ++k) m = fmaxf(m, logits[k]);
        float e = expf(logits[tid] - m);
        float d = 0.0f;
        for (int k = 0; k < NC; ++k) d += expf(logits[k] - m);
        out[b*NC + tid] = e / d;
    }
}

extern "C" void kernel_launch(void* const* d_in, const int* in_sizes, int n_in,
                              void* d_out, int out_size, void* d_ws, size_t ws_size,
                              hipStream_t stream) {
    const float* x      = (const float*)d_in[0];
    const float* conv_w = (const float*)d_in[1];
    const float* conv_b = (const float*)d_in[2];
    const float* wk     = (const float*)d_in[3];
    const float* wr     = (const float*)d_in[4];
    const float* bias   = (const float*)d_in[5];
    const float* dw     = (const float*)d_in[6];
    const float* db     = (const float*)d_in[7];
    float* out = (float*)d_out;

    float* ws     = (float*)d_ws;
    float* pooled = ws;                                   // 6,422,528 f
    float* hA     = pooled + POOLED_ELEMS;                //   373,248 f
    float* hB     = hA + HSTATE_ELEMS;
    float* wpack  = hB + HSTATE_ELEMS;                    //    18,432 f
    __hip_bfloat16* zx = (__hip_bfloat16*)(wpack + WPACK_ELEMS); // 47.8 MB
    unsigned* barriers = (unsigned*)(zx + (size_t)64 * NPT);     // 16 u32

    // h0 = 0 (read as t=0 halo); barrier counters = 0.  (ws poisoned 0xAA)
    hipMemsetAsync(hA, 0, HSTATE_ELEMS * sizeof(float), stream);
    hipMemsetAsync(barriers, 0, TT * sizeof(unsigned), stream);

    repack_kernel<<<dim3(72), dim3(256), 0, stream>>>(wk, wr, wpack);
    conv_pool_kernel<<<dim3(1568), dim3(256), 0, stream>>>(x, conv_w, conv_b, pooled);
    zx_all_kernel<<<dim3(1458, 4), dim3(256), 0, stream>>>(pooled, wpack, zx);

    const float* wrpack = wpack + 9216;
    lstm_scan_kernel<<<dim3(NBLK), dim3(256), 0, stream>>>(
        zx, hA, hB, wrpack, bias, barriers);

    // t=15 (odd) wrote hA
    head_kernel<<<dim3(8), dim3(256), 0, stream>>>(hA, dw, db, out);
}

// Round 10
// 481.324 us; speedup vs baseline: 2.9515x; 2.9515x over previous
//
#include <hip/hip_runtime.h>
#include <hip/hip_bf16.h>
#include <math.h>

// Problem dims
#define BB 8
#define TT 16
#define HH 112
#define WW 112
#define CC 3
#define FF 16
#define HP 56
#define WP 56
#define HO 54
#define WO 54
#define NC 6

#define NPIX (BB*HO*WO)               // 23328
#define SPIX (HO*WO)                  // 2916
#define NPT  (BB*TT*SPIX)             // 373248  (b,t,pixel)

// ws layout (float offsets)
#define POOLED_ELEMS (128*56*56*16)   // 6,422,528
#define HSTATE_ELEMS (BB*SPIX*16)     // 373,248
// wkpack [4 cg][9 tap][16 ci][4 c4][4 g] = 9216
// wrpack [8 cg][9 tap][16 ci][2 c][4 g]  = 9216   -> 18432 total
#define WPACK_ELEMS  18432

typedef __attribute__((ext_vector_type(2))) float f2;   // -> v_pk_fma_f32

__device__ __forceinline__ float hsig(float x) {
    return fminf(fmaxf(0.2f*x + 0.5f, 0.0f), 1.0f);
}
__device__ __forceinline__ f2 f2max(f2 a, f2 b) {
    f2 r; r.x = fmaxf(a.x, b.x); r.y = fmaxf(a.y, b.y); return r;
}

// Kernel 0: repack LSTM weights.
//   wkpack (zx consumer):  [cg4][tap][ci][c4][g]
//   wrpack (step consumer):[cg8][tap][ci][c2][g]   (gate pairs contiguous -> f2)
__global__ __launch_bounds__(256) void repack_kernel(
    const float* __restrict__ wk, const float* __restrict__ wr,
    float* __restrict__ wpack)
{
    int i = blockIdx.x * 256 + threadIdx.x;        // 72*256 = 18432 exact
    if (i < 9216) {
        int g   = i & 3;
        int c4  = (i >> 2) & 3;
        int ci  = (i >> 4) & 15;
        int tap = (i >> 8) % 9;
        int cg  = (i >> 8) / 9;
        wpack[i] = wk[tap*1024 + ci*64 + g*16 + cg*4 + c4];
    } else {
        int j   = i - 9216;
        int g   = j & 3;
        int c   = (j >> 2) & 1;
        int ci  = (j >> 3) & 15;
        int tap = (j >> 7) % 9;
        int cg8 = (j >> 7) / 9;
        wpack[i] = wr[tap*1024 + ci*64 + g*16 + cg8*2 + c];
    }
}

// Kernel 1: fused 7x7 SAME conv (3->16) + bias + relu + 2x2 maxpool.
// fo-pairs as f2 -> packed FMA (weights contiguous in fo).
__global__ __launch_bounds__(256) void conv_pool_kernel(
    const float* __restrict__ x,      // [128,112,112,3]
    const float* __restrict__ cw,     // [7,7,3,16]
    const float* __restrict__ cb,     // [16]
    float* __restrict__ pooled)       // [128,56,56,16]
{
    int idx = blockIdx.x * 256 + threadIdx.x;   // 401408 exact
    int fr = idx / (HP*WP);
    int r  = idx % (HP*WP);
    int ph = r / WP, pw = r % WP;

    const float* xf = x + (size_t)fr * HH * WW * CC;
    const f2* cb2 = (const f2*)cb;

    f2 best[8];
    #pragma unroll
    for (int i = 0; i < 8; ++i) { best[i].x = -1e30f; best[i].y = -1e30f; }

    for (int py = 0; py < 2; ++py) {
        for (int px = 0; px < 2; ++px) {
            int oh = 2*ph + py, ow = 2*pw + px;
            f2 acc[8];
            #pragma unroll
            for (int i = 0; i < 8; ++i) acc[i] = cb2[i];
            for (int ky = 0; ky < 7; ++ky) {
                int ih = oh - 3 + ky;
                if (ih < 0 || ih >= HH) continue;
                for (int kx = 0; kx < 7; ++kx) {
                    int iw = ow - 3 + kx;
                    if (iw < 0 || iw >= WW) continue;
                    const float* xp = xf + ((size_t)ih * WW + iw) * CC;
                    const float* wp = cw + ((ky*7 + kx) * CC) * 16;
                    #pragma unroll
                    for (int ci = 0; ci < 3; ++ci) {
                        float a = xp[ci];
                        const f2* wv = (const f2*)(wp + ci*16);
                        #pragma unroll
                        for (int i = 0; i < 8; ++i)
                            acc[i] += a * wv[i];
                    }
                }
            }
            #pragma unroll
            for (int i = 0; i < 8; ++i) best[i] = f2max(best[i], acc[i]);
        }
    }

    float4* op = (float4*)(pooled + (size_t)idx * 16);
    #pragma unroll
    for (int v = 0; v < 4; ++v) {
        float4 o;
        o.x = fmaxf(best[v*2+0].x, 0.0f);
        o.y = fmaxf(best[v*2+0].y, 0.0f);
        o.z = fmaxf(best[v*2+1].x, 0.0f);
        o.w = fmaxf(best[v*2+1].y, 0.0f);
        op[v] = o;
    }
}

// Kernel 2a: precompute zx = conv3x3 VALID (pooled -> 64 gates) for ALL t.
// Gate pairs as f2 -> packed FMA.
__global__ __launch_bounds__(256, 4) void zx_all_kernel(
    const float* __restrict__ pooled,   // [128,56,56,16]
    const float* __restrict__ wkpack,   // [cg4][tap][ci][c4][g]
    __hip_bfloat16* __restrict__ zx)    // [64][373248]
{
    int cg = blockIdx.y;                // 0..3 (channels cg*4 .. cg*4+3)
    const float* wcg = wkpack + cg * 2304;

    int pt = blockIdx.x * 256 + threadIdx.x;   // 1458*256 = 373248 exact
    int b  = pt / (TT*SPIX);
    int rt = pt % (TT*SPIX);
    int tt = rt / SPIX;
    int r  = rt % SPIX;
    int oh = r / WO, ow = r % WO;

    const float* pf = pooled + (size_t)(b*TT + tt) * HP * WP * 16;

    f2 acc[8];                          // [c4][gpair]
    #pragma unroll
    for (int i = 0; i < 8; ++i) { acc[i].x = 0.f; acc[i].y = 0.f; }

    #pragma unroll 1
    for (int tap = 0; tap < 9; ++tap) {
        int ky = tap / 3;
        int kx = tap - ky * 3;
        const float4* pp = (const float4*)(pf + ((size_t)(oh+ky) * WP + (ow+kx)) * 16);
        float a[16];
        #pragma unroll
        for (int v = 0; v < 4; ++v) {
            float4 x4 = pp[v];
            a[v*4+0] = x4.x; a[v*4+1] = x4.y; a[v*4+2] = x4.z; a[v*4+3] = x4.w;
        }
        const float* wt = wcg + tap * 256;
        #pragma unroll 1
        for (int q = 0; q < 4; ++q) {       // 64 scalar floats live per chunk
            const f2* wv = (const f2*)(wt + q * 64);
            #pragma unroll
            for (int u = 0; u < 4; ++u) {
                float av = a[q*4 + u];
                #pragma unroll
                for (int c4 = 0; c4 < 4; ++c4) {
                    acc[c4*2+0] += av * wv[u*8 + c4*2 + 0];
                    acc[c4*2+1] += av * wv[u*8 + c4*2 + 1];
                }
            }
        }
    }

    #pragma unroll
    for (int c4 = 0; c4 < 4; ++c4) {
        f2 e01 = acc[c4*2+0];
        f2 e23 = acc[c4*2+1];
        zx[(size_t)( 0 + cg*4 + c4) * NPT + pt] = __float2bfloat16(e01.x);
        zx[(size_t)(16 + cg*4 + c4) * NPT + pt] = __float2bfloat16(e01.y);
        zx[(size_t)(32 + cg*4 + c4) * NPT + pt] = __float2bfloat16(e23.x);
        zx[(size_t)(48 + cg*4 + c4) * NPT + pt] = __float2bfloat16(e23.y);
    }
}

// Kernel 2b: one ConvLSTM step. Block = 18x14 pixel tile x 2-channel group
// (blockIdx.z = cg 0..7 -> scalar weights; 768 blocks = 12 waves/CU for
// latency hiding). h tile staged PLANAR: htileV[v][pix] so tap reads have
// 16B lane stride -> conflict-free ds_read_b128 (R7/R8 layout had 64B lane
// stride = 16-way conflicts, SQ_LDS_BANK_CONFLICT 1.4e7). Packed FMA on
// gate pairs. Grid barrier approach abandoned (R8: 61 us/step in one-line
// atomic contention).
__global__ __launch_bounds__(256, 4) void lstm_step_kernel(
    const __hip_bfloat16* __restrict__ zx,  // [64][373248]
    const float* __restrict__ h_in,         // [8,54,54,16]
    float* __restrict__ h_out,
    float* __restrict__ cst,
    const float* __restrict__ wrpack,       // [cg8][tap][ci][c2][g]
    const float* __restrict__ bias,         // [64]
    int t)
{
    int tileid = blockIdx.x;      // 0..11
    int tx = tileid % 3;          // 3 tiles x 18 cols = 54 exact
    int ty = tileid / 3;          // 4 tiles x 14 rows (covers 56, top 2 idle)
    int b  = blockIdx.y;
    int cg = blockIdx.z;          // 0..7, channels cg*2, cg*2+1
    const float* wcg = wrpack + cg * 1152;

    int tid = threadIdx.x;
    int lx = tid % 18, ly = tid / 18;   // ly 0..14 (tid<252)
    int gx = tx*18 + lx;                // 0..53 always
    int gy = ty*14 + ly;
    bool active = (tid < 252) && (gy < HO);

    const float* hb = h_in + (size_t)b * SPIX * 16;

    // Stage h halo tile PLANAR: htileV[v][iy*20+ix] = h[pixel][v*4..v*4+3].
    __shared__ float4 htileV[4][320];   // 20.5 KB
    {
        int gy0 = ty*14 - 1, gx0 = tx*18 - 1;
        for (int i = tid; i < 320; i += 256) {
            int iy = i / 20, ix = i % 20;
            int hy = gy0 + iy, hx = gx0 + ix;
            bool ok = (hy >= 0) & (hy < HO) & (hx >= 0) & (hx < WO);
            const float4* src = (const float4*)(hb + ((size_t)hy * WO + hx) * 16);
            #pragma unroll
            for (int v = 0; v < 4; ++v)
                htileV[v][i] = ok ? src[v] : make_float4(0.f, 0.f, 0.f, 0.f);
        }
    }
    __syncthreads();

    if (!active) return;

    int r = gy * WO + gx;
    size_t pt = (size_t)b * (TT*SPIX) + (size_t)t * SPIX + r;
    int ch0 = cg * 2;

    float z[8];                         // [c][g]
    #pragma unroll
    for (int c = 0; c < 2; ++c)
        #pragma unroll
        for (int g = 0; g < 4; ++g)
            z[c*4 + g] = __bfloat162float(zx[(size_t)(g*16 + ch0 + c) * NPT + pt]);

    f2 acc[4];                          // [c][gpair]
    #pragma unroll
    for (int i = 0; i < 4; ++i) { acc[i].x = 0.f; acc[i].y = 0.f; }

    #pragma unroll 1
    for (int tap = 0; tap < 9; ++tap) {
        int ky = tap / 3;
        int kx = tap - ky * 3;
        int pix = (ly + ky)*20 + (lx + kx);
        float h[16];
        #pragma unroll
        for (int v = 0; v < 4; ++v) {
            float4 t4 = htileV[v][pix];   // 16B lane stride: conflict-free
            h[v*4+0] = t4.x; h[v*4+1] = t4.y; h[v*4+2] = t4.z; h[v*4+3] = t4.w;
        }
        const float* wt = wcg + tap * 128;
        #pragma unroll 1
        for (int hf = 0; hf < 2; ++hf) {    // 64 scalar floats live per chunk
            const f2* wv = (const f2*)(wt + hf * 64);
            #pragma unroll
            for (int u = 0; u < 8; ++u) {
                float hv = h[hf*8 + u];
                acc[0] += hv * wv[u*4 + 0];
                acc[1] += hv * wv[u*4 + 1];
                acc[2] += hv * wv[u*4 + 2];
                acc[3] += hv * wv[u*4 + 3];
            }
        }
    }

    size_t base = ((size_t)(b * SPIX + r)) * 16 + ch0;
    float2 cold = *(float2*)&cst[base];
    float cn[2], hn[2];
    #pragma unroll
    for (int c = 0; c < 2; ++c) {
        float iv = hsig(z[c*4+0] + acc[c*2+0].x + bias[ 0 + ch0 + c]);
        float fv = hsig(z[c*4+1] + acc[c*2+0].y + bias[16 + ch0 + c]);
        float gv = tanhf(z[c*4+2] + acc[c*2+1].x + bias[32 + ch0 + c]);
        float ov = hsig(z[c*4+3] + acc[c*2+1].y + bias[48 + ch0 + c]);
        float cold_c = (c == 0) ? cold.x : cold.y;
        cn[c] = fv * cold_c + iv * gv;
        hn[c] = ov * tanhf(cn[c]);
    }
    *(float2*)&cst[base]   = make_float2(cn[0], cn[1]);
    *(float2*)&h_out[base] = make_float2(hn[0], hn[1]);
}

// Kernel 3: spatial mean over 54x54 -> dense(16->6) -> softmax. One block per b.
__global__ __launch_bounds__(256) void head_kernel(
    const float* __restrict__ h,    // [8,54,54,16]
    const float* __restrict__ dw,   // [16,6]
    const float* __restrict__ db,   // [6]
    float* __restrict__ out)        // [8,6]
{
    int b = blockIdx.x;
    int tid = threadIdx.x;
    const float* hb = h + (size_t)b * SPIX * 16;
    float s = 0.0f;
    for (int i = tid; i < SPIX*16; i += 256) s += hb[i];
    __shared__ float red[256];
    red[tid] = s;
    __syncthreads();
    for (int st = 128; st >= 16; st >>= 1) {
        if (tid < st) red[tid] += red[tid + st];
        __syncthreads();
    }
    __shared__ float logits[8];
    if (tid < NC) {
        float l = db[tid];
        #pragma unroll
        for (int ch = 0; ch < 16; ++ch)
            l += (red[ch] * (1.0f/2916.0f)) * dw[ch*NC + tid];
        logits[tid] = l;
    }
    __syncthreads();
    if (tid < NC) {
        float m = -1e30f;
        for (int k = 0; k < NC; ++k) m = fmaxf(m, logits[k]);
        float e = expf(logits[tid] - m);
        float d = 0.0f;
        for (int k = 0; k < NC; ++k) d += expf(logits[k] - m);
        out[b*NC + tid] = e / d;
    }
}

extern "C" void kernel_launch(void* const* d_in, const int* in_sizes, int n_in,
                              void* d_out, int out_size, void* d_ws, size_t ws_size,
                              hipStream_t stream) {
    const float* x      = (const float*)d_in[0];
    const float* conv_w = (const float*)d_in[1];
    const float* conv_b = (const float*)d_in[2];
    const float* wk     = (const float*)d_in[3];
    const float* wr     = (const float*)d_in[4];
    const float* bias   = (const float*)d_in[5];
    const float* dw     = (const float*)d_in[6];
    const float* db     = (const float*)d_in[7];
    float* out = (float*)d_out;

    float* ws     = (float*)d_ws;
    float* pooled = ws;                                   // 6,422,528 f
    float* hA     = pooled + POOLED_ELEMS;                //   373,248 f
    float* hB     = hA + HSTATE_ELEMS;
    float* cbuf   = hB + HSTATE_ELEMS;
    float* wpack  = cbuf + HSTATE_ELEMS;                  //    18,432 f
    __hip_bfloat16* zx = (__hip_bfloat16*)(wpack + WPACK_ELEMS); // 47.8 MB

    // h0 = 0, c0 = 0 (ws is poisoned before every launch)
    hipMemsetAsync(hA,   0, HSTATE_ELEMS * sizeof(float), stream);
    hipMemsetAsync(cbuf, 0, HSTATE_ELEMS * sizeof(float), stream);

    repack_kernel<<<dim3(72), dim3(256), 0, stream>>>(wk, wr, wpack);
    conv_pool_kernel<<<dim3(1568), dim3(256), 0, stream>>>(x, conv_w, conv_b, pooled);
    zx_all_kernel<<<dim3(1458, 4), dim3(256), 0, stream>>>(pooled, wpack, zx);

    const float* wrpack = wpack + 9216;
    for (int t = 0; t < TT; ++t) {
        const float* hin  = (t & 1) ? hB : hA;
        float*       hout = (t & 1) ? hA : hB;
        lstm_step_kernel<<<dim3(12, 8, 8), dim3(256), 0, stream>>>(
            zx, hin, hout, cbuf, wrpack, bias, t);
    }
    // t=15 (odd) wrote hA
    head_kernel<<<dim3(8), dim3(256), 0, stream>>>(hA, dw, db, out);
}